// Round 8
// baseline (178.368 us; speedup 1.0000x reference)
//
#include <hip/hip_runtime.h>
#include <hip/hip_bf16.h>
#include <math.h>

#define L_TAU_C 0.8f

typedef _Float16 half2_t __attribute__((ext_vector_type(2)));

union U32H2 { unsigned int u; half2_t h; };
__device__ __forceinline__ half2_t h2(unsigned int v) { U32H2 x; x.u = v; return x.h; }

__device__ __forceinline__ float sigmoidf_(float x) {
    return 1.0f / (1.0f + __expf(-x));
}

// ---------------------------------------------------------------------------
// Kernel 1: transpose x [128][4096][20] f32 -> xT [128][20][4096] f16.
// ---------------------------------------------------------------------------
__global__ __launch_bounds__(256) void k_transpose16(const float* __restrict__ x,
                                                     _Float16* __restrict__ xT) {
    int gp = blockIdx.x * 256 + threadIdx.x;      // 0..524287
    int b = gp >> 12, p = gp & 4095;
    const float4* src = reinterpret_cast<const float4*>(x + (size_t)gp * 20);
    float v[20];
#pragma unroll
    for (int k = 0; k < 5; ++k) {
        float4 q = src[k];
        v[4 * k + 0] = q.x; v[4 * k + 1] = q.y; v[4 * k + 2] = q.z; v[4 * k + 3] = q.w;
    }
    _Float16* dst = xT + (size_t)b * 20 * 4096 + p;
#pragma unroll
    for (int t = 0; t < 20; ++t) dst[(size_t)t * 4096] = (_Float16)v[t];
}

// ---------------------------------------------------------------------------
// Kernel 2: fused conv + SNU(s1,y1) + maxpool + partial FC dot.
// BARRIERLESS / NO-LDS design: the per-(b,t) x slice is 8 KB -> L1/L2
// resident (all 6 ch of a b run on the same XCD via swizzle; 5/6 reads are
// cache hits). Each thread reads its conv window DIRECTLY from global:
// no staging, no double buffer, no __syncthreads -- every wave runs its
// whole 20-step recurrence autonomously; per-wave partials go to global.
// Grid = 768 (b,ch); block = 192 (3 waves), 189 active:
// thread = (pool row r 0..26, col group g 0..6) -> 2 conv rows x 8 cols
// (g=6: cols 48..55, 54/55 junk -> masked by w2r=0).
// Window start = half 8g = byte 16g -> 16B-aligned: per conv row
// 2 x global_load_dwordx4 + 1 dword (17th half; address-clamped for g=6).
// Conv weights packed half2 in SGPRs (readfirstlane, proven R7);
// v_dot2_f32_f16 datapath with v_alignbit odd-column shifts (proven R5/R6).
// ---------------------------------------------------------------------------
template<int XMODE>   // 1 = f16 transposed input, 0 = strided f32 fallback
__global__ __launch_bounds__(192, 4) void k_conv_snu(
    const float* __restrict__ x,      // [128][4096][20]
    const _Float16* __restrict__ xT,  // [128][20][4096]
    const float* __restrict__ Wc,     // [6][1][10][10]
    const float* __restrict__ bc,     // [6]
    const float* __restrict__ W2,     // [4374][2]
    float* __restrict__ partw)        // [20][128][6][3][2]
{
    const int tid = threadIdx.x;
    const int bi = blockIdx.x;
    const int xcd = bi & 7, slot = bi >> 3;
    const int b = (slot / 6) * 8 + xcd;   // all 6 ch of b on same XCD (L2/L1 reuse)
    const int ch = slot % 6;

    const bool active = tid < 189;
    const int r = tid / 7;            // pool row 0..26
    const int g = tid % 7;            // col group: conv cols 8g..8g+7
    const int row0 = 2 * r;

    // ---- weights -> SGPRs (one-time, uniform) ----
    const float* wb = Wc + ch * 100;
    unsigned int wsg[50];
#pragma unroll
    for (int i = 0; i < 50; ++i) {
        U32H2 pk;
        pk.h = half2_t{(_Float16)wb[2 * i], (_Float16)wb[2 * i + 1]};
        wsg[i] = (unsigned int)__builtin_amdgcn_readfirstlane((int)pk.u);
    }

    float s1[2][8], y1[2][8];
#pragma unroll
    for (int i = 0; i < 2; ++i)
#pragma unroll
        for (int j = 0; j < 8; ++j) { s1[i][j] = 0.f; y1[i][j] = 0.f; }

    const float bch = bc[ch];

    // FC weights for this thread's 4 pool cols (pc = 4g+pj; pc>=27 masked 0)
    float w2r[4][2];
#pragma unroll
    for (int pj = 0; pj < 4; ++pj) { w2r[pj][0] = 0.f; w2r[pj][1] = 0.f; }
    if (active) {
#pragma unroll
        for (int pj = 0; pj < 4; ++pj) {
            int pc = 4 * g + pj;
            if (pc < 27) {
                int f0 = ch * 729 + r * 27 + pc;
                w2r[pj][0] = W2[(size_t)f0 * 2 + 0];
                w2r[pj][1] = W2[(size_t)f0 * 2 + 1];
            }
        }
    }

    const _Float16* xb16 = xT + (size_t)b * 20 * 4096;
    const float* xb32 = x + (size_t)b * 4096 * 20;
    const int off17 = (g < 6) ? 16 : 14;   // clamp 17th-half addr in-row for g=6

    for (int t = 0; t < 20; ++t) {
        float p0 = 0.f, p1 = 0.f;
        if (active) {
            float c0[8], c1[8];
#pragma unroll
            for (int j = 0; j < 8; ++j) { c0[j] = 0.f; c1[j] = 0.f; }

#pragma unroll
            for (int xr = 0; xr < 11; ++xr) {
                const int R = row0 + xr;
                unsigned int s[9];
                if (XMODE == 1) {
                    const _Float16* rp = xb16 + (size_t)t * 4096 + R * 64 + 8 * g;
                    uint4 A = *reinterpret_cast<const uint4*>(rp);       // halfs 0..7
                    uint4 B = *reinterpret_cast<const uint4*>(rp + 8);   // halfs 8..15
                    unsigned int C = *reinterpret_cast<const unsigned int*>(rp + off17);
                    s[0] = A.x; s[1] = A.y; s[2] = A.z; s[3] = A.w;
                    s[4] = B.x; s[5] = B.y; s[6] = B.z; s[7] = B.w;
                    s[8] = C;
                } else {
                    const float* rp = xb32 + ((size_t)R * 64 + 8 * g) * 20 + t;
#pragma unroll
                    for (int q = 0; q < 8; ++q) {
                        U32H2 pk;
                        pk.h = half2_t{(_Float16)rp[(2 * q) * 20],
                                       (_Float16)rp[(2 * q + 1) * 20]};
                        s[q] = pk.u;
                    }
                    {
                        U32H2 pk;
                        pk.h = half2_t{(_Float16)rp[off17 * 20],
                                       (_Float16)rp[(off17 + 1) * 20]};
                        s[8] = pk.u;
                    }
                }
                unsigned int ss[8];
#pragma unroll
                for (int i = 0; i < 8; ++i)
                    ss[i] = (s[i] >> 16) | (s[i + 1] << 16);   // v_alignbit

                if (xr <= 9) {
#pragma unroll
                    for (int m = 0; m < 5; ++m) {
                        half2_t w = h2(wsg[xr * 5 + m]);
                        c0[0] = __builtin_amdgcn_fdot2(h2(s[m]),      w, c0[0], false);
                        c0[1] = __builtin_amdgcn_fdot2(h2(ss[m]),     w, c0[1], false);
                        c0[2] = __builtin_amdgcn_fdot2(h2(s[m + 1]),  w, c0[2], false);
                        c0[3] = __builtin_amdgcn_fdot2(h2(ss[m + 1]), w, c0[3], false);
                        c0[4] = __builtin_amdgcn_fdot2(h2(s[m + 2]),  w, c0[4], false);
                        c0[5] = __builtin_amdgcn_fdot2(h2(ss[m + 2]), w, c0[5], false);
                        c0[6] = __builtin_amdgcn_fdot2(h2(s[m + 3]),  w, c0[6], false);
                        c0[7] = __builtin_amdgcn_fdot2(h2(ss[m + 3]), w, c0[7], false);
                    }
                }
                if (xr >= 1) {
#pragma unroll
                    for (int m = 0; m < 5; ++m) {
                        half2_t w = h2(wsg[(xr - 1) * 5 + m]);
                        c1[0] = __builtin_amdgcn_fdot2(h2(s[m]),      w, c1[0], false);
                        c1[1] = __builtin_amdgcn_fdot2(h2(ss[m]),     w, c1[1], false);
                        c1[2] = __builtin_amdgcn_fdot2(h2(s[m + 1]),  w, c1[2], false);
                        c1[3] = __builtin_amdgcn_fdot2(h2(ss[m + 1]), w, c1[3], false);
                        c1[4] = __builtin_amdgcn_fdot2(h2(s[m + 2]),  w, c1[4], false);
                        c1[5] = __builtin_amdgcn_fdot2(h2(ss[m + 2]), w, c1[5], false);
                        c1[6] = __builtin_amdgcn_fdot2(h2(s[m + 3]),  w, c1[6], false);
                        c1[7] = __builtin_amdgcn_fdot2(h2(ss[m + 3]), w, c1[7], false);
                    }
                }
            }
            // SNU: s = relu(c + 0.8*s*(1-y)); y = sigmoid(s + bc)
#pragma unroll
            for (int j = 0; j < 8; ++j) {
                float sa = fmaxf(c0[j] + L_TAU_C * s1[0][j] * (1.f - y1[0][j]), 0.f);
                float sb = fmaxf(c1[j] + L_TAU_C * s1[1][j] * (1.f - y1[1][j]), 0.f);
                s1[0][j] = sa; s1[1][j] = sb;
                y1[0][j] = sigmoidf_(sa + bch);
                y1[1][j] = sigmoidf_(sb + bch);
            }
            // maxpool 2x2 + partial FC dot (4 pool cols)
#pragma unroll
            for (int pj = 0; pj < 4; ++pj) {
                float h = fmaxf(fmaxf(y1[0][2 * pj], y1[0][2 * pj + 1]),
                                fmaxf(y1[1][2 * pj], y1[1][2 * pj + 1]));
                p0 += h * w2r[pj][0];
                p1 += h * w2r[pj][1];
            }
        }
        // wave reduce -> direct global store of per-wave partials
#pragma unroll
        for (int off = 32; off >= 1; off >>= 1) {
            p0 += __shfl_down(p0, off);
            p1 += __shfl_down(p1, off);
        }
        if ((tid & 63) == 0) {
            float2 val; val.x = p0; val.y = p1;
            *reinterpret_cast<float2*>(
                &partw[((((size_t)t * 128 + b) * 6 + ch) * 3 + (tid >> 6)) * 2]) = val;
        }
    }
}

// ---------------------------------------------------------------------------
// Kernel 3: s2/y2 recurrence, out_rec, m, loss, acc. One block, 128 threads.
// ---------------------------------------------------------------------------
__global__ __launch_bounds__(128) void k_final(const float* __restrict__ partw,
                                               const void* __restrict__ yraw,
                                               const float* __restrict__ b2,
                                               float* __restrict__ out) {
    __shared__ float red[4];
    const int b = threadIdx.x;  // 0..127

    // labels may be int64 (reference) or int32: detect.
    const int* yi = (const int*)yraw;
    bool i64 = true;
    for (int k = 0; k < 64; ++k) {
        if (yi[2 * k + 1] != 0) { i64 = false; break; }
    }
    int lbl = i64 ? (int)((const long long*)yraw)[b] : yi[b];

    float b20 = b2[0], b21 = b2[1];
    float s20 = 0.f, s21 = 0.f, y20 = 0.f, y21 = 0.f, m0 = 0.f, m1 = 0.f;
    float* orec = out + 257 + b * 42;
    orec[0] = 0.f; orec[1] = 0.f;
    for (int t = 0; t < 20; ++t) {
        const float4* pp = reinterpret_cast<const float4*>(
            partw + ((size_t)t * 128 + b) * 36);
        float sum0 = 0.f, sum1 = 0.f;
#pragma unroll
        for (int i = 0; i < 9; ++i) {
            float4 a = pp[i];
            sum0 += a.x + a.z;
            sum1 += a.y + a.w;
        }
        s20 = fmaxf(sum0 + L_TAU_C * s20 * (1.f - y20), 0.f);
        s21 = fmaxf(sum1 + L_TAU_C * s21 * (1.f - y21), 0.f);
        y20 = sigmoidf_(s20 + b20);
        y21 = sigmoidf_(s21 + b21);
        orec[(t + 1) * 2 + 0] = y20;
        orec[(t + 1) * 2 + 1] = y21;
        m0 += y20; m1 += y21;
    }
    m0 *= 0.05f; m1 *= 0.05f;
    out[1 + b * 2 + 0] = m0;
    out[1 + b * 2 + 1] = m1;

    float mx = fmaxf(m0, m1);
    float lse = mx + logf(expf(m0 - mx) + expf(m1 - mx));
    float lossc = -(((lbl != 0) ? m1 : m0) - lse);
    int pred = (m1 > m0) ? 1 : 0;
    float accc = (pred == lbl) ? 1.f : 0.f;
#pragma unroll
    for (int off = 32; off >= 1; off >>= 1) {
        lossc += __shfl_down(lossc, off);
        accc += __shfl_down(accc, off);
    }
    if ((b & 63) == 0) { red[(b >> 6) * 2] = lossc; red[(b >> 6) * 2 + 1] = accc; }
    __syncthreads();
    if (b == 0) {
        out[0] = (red[0] + red[2]) * (1.f / 128.f);
        out[5633] = (red[1] + red[3]) * (1.f / 128.f);
    }
}

extern "C" void kernel_launch(void* const* d_in, const int* in_sizes, int n_in,
                              void* d_out, int out_size, void* d_ws, size_t ws_size,
                              hipStream_t stream) {
    const float* x  = (const float*)d_in[0];
    const void*  y  = d_in[1];
    const float* Wc = (const float*)d_in[2];
    const float* bc = (const float*)d_in[3];
    const float* W2 = (const float*)d_in[4];
    const float* b2 = (const float*)d_in[5];
    float* out = (float*)d_out;

    const size_t xt_bytes = (size_t)128 * 20 * 4096 * 2;         // 20,971,520
    const size_t partw_bytes = (size_t)20 * 128 * 6 * 3 * 2 * 4; // 368,640
    const int use16 = (ws_size >= xt_bytes + partw_bytes) ? 1 : 0;

    _Float16* xT = (_Float16*)d_ws;
    float* partw = use16 ? (float*)((char*)d_ws + xt_bytes) : (float*)d_ws;

    if (use16) {
        k_transpose16<<<2048, 256, 0, stream>>>(x, xT);
        k_conv_snu<1><<<768, 192, 0, stream>>>(x, xT, Wc, bc, W2, partw);
    } else {
        k_conv_snu<0><<<768, 192, 0, stream>>>(x, (const _Float16*)d_ws, Wc, bc, W2, partw);
    }
    k_final<<<1, 128, 0, stream>>>(partw, y, b2, out);
}

// Round 9
// 159.857 us; speedup vs baseline: 1.1158x; 1.1158x over previous
//
#include <hip/hip_runtime.h>
#include <hip/hip_bf16.h>
#include <math.h>

#define L_TAU_C 0.8f

typedef _Float16 half2_t __attribute__((ext_vector_type(2)));

union U32H2 { unsigned int u; half2_t h; };
__device__ __forceinline__ half2_t h2(unsigned int v) { U32H2 x; x.u = v; return x.h; }

__device__ __forceinline__ float sigmoidf_(float x) {
    return 1.0f / (1.0f + __expf(-x));
}

// ---------------------------------------------------------------------------
// Kernel 1: transpose x [128][4096][20] f32 -> xT [128][20][4096] f16.
// ---------------------------------------------------------------------------
__global__ __launch_bounds__(256) void k_transpose16(const float* __restrict__ x,
                                                     _Float16* __restrict__ xT) {
    int gp = blockIdx.x * 256 + threadIdx.x;      // 0..524287
    int b = gp >> 12, p = gp & 4095;
    const float4* src = reinterpret_cast<const float4*>(x + (size_t)gp * 20);
    float v[20];
#pragma unroll
    for (int k = 0; k < 5; ++k) {
        float4 q = src[k];
        v[4 * k + 0] = q.x; v[4 * k + 1] = q.y; v[4 * k + 2] = q.z; v[4 * k + 3] = q.w;
    }
    _Float16* dst = xT + (size_t)b * 20 * 4096 + p;
#pragma unroll
    for (int t = 0; t < 20; ++t) dst[(size_t)t * 4096] = (_Float16)v[t];
}

// ---------------------------------------------------------------------------
// Kernel 2: fused conv + SNU(s1,y1) + maxpool + partial FC dot.
// FINE-GRAINED BARRIERLESS: cross-round evidence (R6 LDS@3w/SIMD=141us,
// R8 noLDS@2.25w/SIMD=165us) says the limiter is latency-hiding, and total
// thread count is what caps occupancy. So: thread = 1 pool row x 2 pool
// cols (8 conv outputs) -> 27x14=378 active / 384-thd blocks, 768 blocks
// = 290K threads = 18 waves/CU (2x R8). No LDS, no barriers: reads come
// straight from L1/L2 (8KB slice/CU stays resident; all 6 ch of b on one
// XCD). Window = u32s [2pcg..2pcg+6] at byte 8*pcg -> 3 uint2 + 1 b32 per
// row, ALL aligned, per-lane stride 8B -> dense TA coalescing.
// Weights in SGPRs (readfirstlane); v_dot2_f32_f16 + v_alignbit datapath.
// Per-wave partials straight to global (6 waves/block).
// ---------------------------------------------------------------------------
template<int XMODE>   // 1 = f16 transposed input, 0 = strided f32 fallback
__global__ __launch_bounds__(384, 2) void k_conv_snu(
    const float* __restrict__ x,      // [128][4096][20]
    const _Float16* __restrict__ xT,  // [128][20][4096]
    const float* __restrict__ Wc,     // [6][1][10][10]
    const float* __restrict__ bc,     // [6]
    const float* __restrict__ W2,     // [4374][2]
    float* __restrict__ partw)        // [20][128][6][6][2]
{
    const int tid = threadIdx.x;
    const int bi = blockIdx.x;
    const int xcd = bi & 7, slot = bi >> 3;
    const int b = (slot / 6) * 8 + xcd;   // all 6 ch of b on same XCD
    const int ch = slot % 6;

    const bool active = tid < 378;
    const int r = tid / 14;           // pool row 0..26
    const int pcg = tid % 14;         // pool col pair: pool cols 2pcg, 2pcg+1
    const int row0 = 2 * r;

    // ---- weights -> SGPRs (one-time, uniform) ----
    const float* wb = Wc + ch * 100;
    unsigned int wsg[50];
#pragma unroll
    for (int i = 0; i < 50; ++i) {
        U32H2 pk;
        pk.h = half2_t{(_Float16)wb[2 * i], (_Float16)wb[2 * i + 1]};
        wsg[i] = (unsigned int)__builtin_amdgcn_readfirstlane((int)pk.u);
    }

    float s1[2][4], y1[2][4];
#pragma unroll
    for (int i = 0; i < 2; ++i)
#pragma unroll
        for (int j = 0; j < 4; ++j) { s1[i][j] = 0.f; y1[i][j] = 0.f; }

    const float bch = bc[ch];

    // FC weights for this thread's 2 pool cols (pc = 2pcg+k; pc>=27 masked 0)
    float w2r[2][2];
    w2r[0][0] = 0.f; w2r[0][1] = 0.f; w2r[1][0] = 0.f; w2r[1][1] = 0.f;
    if (active) {
#pragma unroll
        for (int k = 0; k < 2; ++k) {
            int pc = 2 * pcg + k;
            if (pc < 27) {
                int f0 = ch * 729 + r * 27 + pc;
                w2r[k][0] = W2[(size_t)f0 * 2 + 0];
                w2r[k][1] = W2[(size_t)f0 * 2 + 1];
            }
        }
    }

    const _Float16* xb16 = xT + (size_t)b * 20 * 4096;
    const float* xb32 = x + (size_t)b * 4096 * 20;

    for (int t = 0; t < 20; ++t) {
        float p0 = 0.f, p1 = 0.f;
        if (active) {
            float c0[4] = {0.f, 0.f, 0.f, 0.f};
            float c1[4] = {0.f, 0.f, 0.f, 0.f};

#pragma unroll
            for (int xr = 0; xr < 11; ++xr) {
                const int R = row0 + xr;
                unsigned int s[7];
                if (XMODE == 1) {
                    // byte offset 8*pcg within a 128B row: all loads aligned
                    const _Float16* rp = xb16 + (size_t)t * 4096 + R * 64 + 4 * pcg;
                    uint2 a = *reinterpret_cast<const uint2*>(rp);
                    uint2 bq = *reinterpret_cast<const uint2*>(rp + 4);
                    uint2 cq = *reinterpret_cast<const uint2*>(rp + 8);
                    unsigned int dq = *reinterpret_cast<const unsigned int*>(rp + 12);
                    s[0] = a.x; s[1] = a.y; s[2] = bq.x; s[3] = bq.y;
                    s[4] = cq.x; s[5] = cq.y; s[6] = dq;
                } else {
                    const float* rp = xb32 + ((size_t)R * 64 + 4 * pcg) * 20 + t;
#pragma unroll
                    for (int q = 0; q < 7; ++q) {
                        U32H2 pk;
                        pk.h = half2_t{(_Float16)rp[(2 * q) * 20],
                                       (_Float16)rp[(2 * q + 1) * 20]};
                        s[q] = pk.u;
                    }
                }
                unsigned int ss[6];
#pragma unroll
                for (int i = 0; i < 6; ++i)
                    ss[i] = (s[i] >> 16) | (s[i + 1] << 16);   // v_alignbit

                if (xr <= 9) {
#pragma unroll
                    for (int m = 0; m < 5; ++m) {
                        half2_t w = h2(wsg[xr * 5 + m]);
                        c0[0] = __builtin_amdgcn_fdot2(h2(s[m]),      w, c0[0], false);
                        c0[1] = __builtin_amdgcn_fdot2(h2(ss[m]),     w, c0[1], false);
                        c0[2] = __builtin_amdgcn_fdot2(h2(s[m + 1]),  w, c0[2], false);
                        c0[3] = __builtin_amdgcn_fdot2(h2(ss[m + 1]), w, c0[3], false);
                    }
                }
                if (xr >= 1) {
#pragma unroll
                    for (int m = 0; m < 5; ++m) {
                        half2_t w = h2(wsg[(xr - 1) * 5 + m]);
                        c1[0] = __builtin_amdgcn_fdot2(h2(s[m]),      w, c1[0], false);
                        c1[1] = __builtin_amdgcn_fdot2(h2(ss[m]),     w, c1[1], false);
                        c1[2] = __builtin_amdgcn_fdot2(h2(s[m + 1]),  w, c1[2], false);
                        c1[3] = __builtin_amdgcn_fdot2(h2(ss[m + 1]), w, c1[3], false);
                    }
                }
            }
            // SNU: s = relu(c + 0.8*s*(1-y)); y = sigmoid(s + bc)
#pragma unroll
            for (int j = 0; j < 4; ++j) {
                float sa = fmaxf(c0[j] + L_TAU_C * s1[0][j] * (1.f - y1[0][j]), 0.f);
                float sb = fmaxf(c1[j] + L_TAU_C * s1[1][j] * (1.f - y1[1][j]), 0.f);
                s1[0][j] = sa; s1[1][j] = sb;
                y1[0][j] = sigmoidf_(sa + bch);
                y1[1][j] = sigmoidf_(sb + bch);
            }
            // maxpool 2x2 (2 pool outs) + partial FC dot
            float h0 = fmaxf(fmaxf(y1[0][0], y1[0][1]), fmaxf(y1[1][0], y1[1][1]));
            float h1 = fmaxf(fmaxf(y1[0][2], y1[0][3]), fmaxf(y1[1][2], y1[1][3]));
            p0 = h0 * w2r[0][0] + h1 * w2r[1][0];
            p1 = h0 * w2r[0][1] + h1 * w2r[1][1];
        }
        // wave reduce -> direct global store of per-wave partials
#pragma unroll
        for (int off = 32; off >= 1; off >>= 1) {
            p0 += __shfl_down(p0, off);
            p1 += __shfl_down(p1, off);
        }
        if ((tid & 63) == 0) {
            float2 val; val.x = p0; val.y = p1;
            *reinterpret_cast<float2*>(
                &partw[((((size_t)t * 128 + b) * 6 + ch) * 6 + (tid >> 6)) * 2]) = val;
        }
    }
}

// ---------------------------------------------------------------------------
// Kernel 3: s2/y2 recurrence, out_rec, m, loss, acc. One block, 128 threads.
// ---------------------------------------------------------------------------
__global__ __launch_bounds__(128) void k_final(const float* __restrict__ partw,
                                               const void* __restrict__ yraw,
                                               const float* __restrict__ b2,
                                               float* __restrict__ out) {
    __shared__ float red[4];
    const int b = threadIdx.x;  // 0..127

    // labels may be int64 (reference) or int32: detect.
    const int* yi = (const int*)yraw;
    bool i64 = true;
    for (int k = 0; k < 64; ++k) {
        if (yi[2 * k + 1] != 0) { i64 = false; break; }
    }
    int lbl = i64 ? (int)((const long long*)yraw)[b] : yi[b];

    float b20 = b2[0], b21 = b2[1];
    float s20 = 0.f, s21 = 0.f, y20 = 0.f, y21 = 0.f, m0 = 0.f, m1 = 0.f;
    float* orec = out + 257 + b * 42;
    orec[0] = 0.f; orec[1] = 0.f;
    for (int t = 0; t < 20; ++t) {
        const float4* pp = reinterpret_cast<const float4*>(
            partw + ((size_t)t * 128 + b) * 72);
        float sum0 = 0.f, sum1 = 0.f;
#pragma unroll
        for (int i = 0; i < 18; ++i) {
            float4 a = pp[i];
            sum0 += a.x + a.z;
            sum1 += a.y + a.w;
        }
        s20 = fmaxf(sum0 + L_TAU_C * s20 * (1.f - y20), 0.f);
        s21 = fmaxf(sum1 + L_TAU_C * s21 * (1.f - y21), 0.f);
        y20 = sigmoidf_(s20 + b20);
        y21 = sigmoidf_(s21 + b21);
        orec[(t + 1) * 2 + 0] = y20;
        orec[(t + 1) * 2 + 1] = y21;
        m0 += y20; m1 += y21;
    }
    m0 *= 0.05f; m1 *= 0.05f;
    out[1 + b * 2 + 0] = m0;
    out[1 + b * 2 + 1] = m1;

    float mx = fmaxf(m0, m1);
    float lse = mx + logf(expf(m0 - mx) + expf(m1 - mx));
    float lossc = -(((lbl != 0) ? m1 : m0) - lse);
    int pred = (m1 > m0) ? 1 : 0;
    float accc = (pred == lbl) ? 1.f : 0.f;
#pragma unroll
    for (int off = 32; off >= 1; off >>= 1) {
        lossc += __shfl_down(lossc, off);
        accc += __shfl_down(accc, off);
    }
    if ((b & 63) == 0) { red[(b >> 6) * 2] = lossc; red[(b >> 6) * 2 + 1] = accc; }
    __syncthreads();
    if (b == 0) {
        out[0] = (red[0] + red[2]) * (1.f / 128.f);
        out[5633] = (red[1] + red[3]) * (1.f / 128.f);
    }
}

extern "C" void kernel_launch(void* const* d_in, const int* in_sizes, int n_in,
                              void* d_out, int out_size, void* d_ws, size_t ws_size,
                              hipStream_t stream) {
    const float* x  = (const float*)d_in[0];
    const void*  y  = d_in[1];
    const float* Wc = (const float*)d_in[2];
    const float* bc = (const float*)d_in[3];
    const float* W2 = (const float*)d_in[4];
    const float* b2 = (const float*)d_in[5];
    float* out = (float*)d_out;

    const size_t xt_bytes = (size_t)128 * 20 * 4096 * 2;         // 20,971,520
    const size_t partw_bytes = (size_t)20 * 128 * 6 * 6 * 2 * 4; // 737,280
    const int use16 = (ws_size >= xt_bytes + partw_bytes) ? 1 : 0;

    _Float16* xT = (_Float16*)d_ws;
    float* partw = use16 ? (float*)((char*)d_ws + xt_bytes) : (float*)d_ws;

    if (use16) {
        k_transpose16<<<2048, 256, 0, stream>>>(x, xT);
        k_conv_snu<1><<<768, 384, 0, stream>>>(x, xT, Wc, bc, W2, partw);
    } else {
        k_conv_snu<0><<<768, 384, 0, stream>>>(x, (const _Float16*)d_ws, Wc, bc, W2, partw);
    }
    k_final<<<1, 128, 0, stream>>>(partw, y, b2, out);
}